// Round 1
// baseline (217.745 us; speedup 1.0000x reference)
//
#include <hip/hip_runtime.h>

#define TILE_Y 32
#define TILE_X 64
#define IN_TY 36   // TILE_Y + 4
#define IN_TX 68   // TILE_X + 4
#define PX 8       // pixels per thread along x

// LeNet C3 connection table: input channel ii feeds CONN[ii][j] with weight[j][ii].
__device__ constexpr int CONN[6][10] = {
    {0, 4, 5, 6, 9, 10, 11, 12, 14, 15},
    {0, 1, 5, 6, 7, 10, 11, 12, 13, 15},
    {0, 1, 2, 6, 7, 8, 11, 13, 14, 15},
    {1, 2, 3, 6, 7, 8, 9, 12, 14, 15},
    {2, 3, 4, 7, 8, 9, 10, 12, 13, 15},
    {3, 4, 5, 8, 9, 10, 11, 13, 14, 15}};

// How many lists contain channel c (bias multiplier).
__device__ constexpr int CNT[16] = {3,3,3,3,3,3,4,4,4,4,4,4,4,4,4,6};

__global__ __launch_bounds__(256, 2) void c3_kernel(
    const float* __restrict__ x, const float* __restrict__ w,
    const float* __restrict__ bias, float* __restrict__ out)
{
    __shared__ float s_in[6][IN_TY][IN_TX];  // 58752 B
    __shared__ float s_w[1500];              // 6000 B

    const int tid = threadIdx.x;
    const int bx = blockIdx.x;   // 0..3  x-tiles
    const int by = blockIdx.y;   // 0..7  y-tiles
    const int n  = blockIdx.z;   // 0..63

    const int x0 = bx * TILE_X;
    const int y0 = by * TILE_Y;

    // ---- stage weights (1500 f32, coalesced) ----
    for (int k = tid; k < 1500; k += 256) s_w[k] = w[k];

    // ---- stage input tile as float4 (6*36*17 = 3672 float4) ----
    const float* xin = x + (size_t)n * 6 * 256 * 256;
    for (int f = tid; f < 6 * 36 * 17; f += 256) {
        int c4 = f % 17;
        int t  = f / 17;
        int r  = t % 36;
        int i  = t / 36;
        int grow  = y0 + r;
        int gcol4 = (x0 >> 2) + c4;
        float4 v = make_float4(0.f, 0.f, 0.f, 0.f);
        if (grow < 256 && gcol4 < 64) {
            v = *reinterpret_cast<const float4*>(xin + ((i * 256 + grow) * 256) + (gcol4 * 4));
        }
        *reinterpret_cast<float4*>(&s_in[i][r][c4 * 4]) = v;
    }
    __syncthreads();

    const int tx = tid & 7;   // 8 threads across x, each covers 8 px
    const int ty = tid >> 3;  // 32 rows

    float acc[PX][16];
    #pragma unroll
    for (int p = 0; p < PX; ++p)
        #pragma unroll
        for (int c = 0; c < 16; ++c) acc[p][c] = 0.f;

    #pragma unroll
    for (int ii = 0; ii < 6; ++ii) {
        #pragma unroll 1   // keep code size in check: 6 copies of a 400-FMA body
        for (int r = 0; r < 5; ++r) {
            // 12-wide input window for 8 pixels (3x ds_read_b128, 16B aligned)
            float win[12];
            const float* src = &s_in[ii][ty + r][tx * 8];
            #pragma unroll
            for (int q = 0; q < 3; ++q) {
                float4 v = *reinterpret_cast<const float4*>(src + q * 4);
                win[q * 4 + 0] = v.x; win[q * 4 + 1] = v.y;
                win[q * 4 + 2] = v.z; win[q * 4 + 3] = v.w;
            }
            #pragma unroll
            for (int kx = 0; kx < 5; ++kx) {
                #pragma unroll
                for (int j = 0; j < 10; ++j) {
                    // weight[j][ii][r][kx], uniform address -> LDS broadcast
                    float wv = s_w[(j * 6 + ii) * 25 + r * 5 + kx];
                    const int c = CONN[ii][j];
                    #pragma unroll
                    for (int p = 0; p < PX; ++p)
                        acc[p][c] = fmaf(win[kx + p], wv, acc[p][c]);
                }
            }
        }
    }

    // ---- epilogue: bias*count, guarded float4 stores ----
    const int oy = y0 + ty;
    const int ox = x0 + tx * 8;
    if (oy < 252) {
        float* op = out + (size_t)n * 16 * 63504 + oy * 252 + ox;
        #pragma unroll
        for (int c = 0; c < 16; ++c) {
            float b = bias[c] * (float)CNT[c];
            if (ox + 3 < 252) {
                float4 v = make_float4(acc[0][c] + b, acc[1][c] + b,
                                       acc[2][c] + b, acc[3][c] + b);
                *reinterpret_cast<float4*>(op + (size_t)c * 63504) = v;
            }
            if (ox + 7 < 252) {
                float4 v = make_float4(acc[4][c] + b, acc[5][c] + b,
                                       acc[6][c] + b, acc[7][c] + b);
                *reinterpret_cast<float4*>(op + (size_t)c * 63504 + 4) = v;
            }
        }
    }
}

extern "C" void kernel_launch(void* const* d_in, const int* in_sizes, int n_in,
                              void* d_out, int out_size, void* d_ws, size_t ws_size,
                              hipStream_t stream) {
    const float* x    = (const float*)d_in[0];  // (64,6,256,256)
    const float* w    = (const float*)d_in[1];  // (10,6,5,5)
    const float* bias = (const float*)d_in[2];  // (1,16,1,1)
    float* out = (float*)d_out;                 // (64,16,252,252)

    dim3 grid(4, 8, 64);
    dim3 block(256);
    hipLaunchKernelGGL(c3_kernel, grid, block, 0, stream, x, w, bias, out);
}

// Round 2
// 159.109 us; speedup vs baseline: 1.3685x; 1.3685x over previous
//
#include <hip/hip_runtime.h>

#define IN_T 36            // staged tile: 36 x 36 floats per channel
#define NF4  324           // float4 per channel tile (36*36/4)
#define PX 4               // pixels per thread along x

// LeNet C3 connection table: input channel ii feeds CONN[ii][j] with weight[j][ii].
__device__ constexpr int CONN[6][10] = {
    {0, 4, 5, 6, 9, 10, 11, 12, 14, 15},
    {0, 1, 5, 6, 7, 10, 11, 12, 13, 15},
    {0, 1, 2, 6, 7, 8, 11, 13, 14, 15},
    {1, 2, 3, 6, 7, 8, 9, 12, 14, 15},
    {2, 3, 4, 7, 8, 9, 10, 12, 13, 15},
    {3, 4, 5, 8, 9, 10, 11, 13, 14, 15}};

// How many lists contain channel c (bias multiplier).
__device__ constexpr int CNT[16] = {3,3,3,3,3,3,4,4,4,4,4,4,4,4,4,6};

__global__ __launch_bounds__(256, 4) void c3_kernel(
    const float* __restrict__ x, const float* __restrict__ w,
    const float* __restrict__ bias, float* __restrict__ out)
{
    __shared__ float4 s_in[2][NF4];   // 2 x 5184 B = 10368 B

    const int tid = threadIdx.x;
    const int x0 = blockIdx.x * 32;
    const int y0 = blockIdx.y * 32;
    const int n  = blockIdx.z;
    const float* xin = x + (size_t)n * 6 * 65536;

    // ---- staging addresses (computed once; clamped so OOB rows/cols read
    //      valid-but-garbage data that only feeds discarded outputs) ----
    const int f0 = tid;                 // float4 index 0..255
    const int f1 = tid + 256;           // 256..511 (valid when < 324)
    const bool has2 = (tid < NF4 - 256);

    int r0 = f0 / 9, c0 = f0 % 9;
    int gr0 = y0 + r0; if (gr0 > 255) gr0 = 255;
    int gc0 = (x0 >> 2) + c0; if (gc0 > 63) gc0 = 63;
    const size_t ga0 = (size_t)gr0 * 256 + (size_t)gc0 * 4;

    int r1 = f1 / 9, c1 = f1 % 9;
    int gr1 = y0 + r1; if (gr1 > 255) gr1 = 255;
    int gc1 = (x0 >> 2) + c1; if (gc1 > 63) gc1 = 63;
    const size_t ga1 = (size_t)gr1 * 256 + (size_t)gc1 * 4;

    const int tx = tid & 7;    // 8 threads across x, 4 px each
    const int ty = tid >> 3;   // 32 rows

    float acc[PX][16];
    #pragma unroll
    for (int p = 0; p < PX; ++p)
        #pragma unroll
        for (int c = 0; c < 16; ++c) acc[p][c] = 0.f;

    // ---- prologue: stage channel 0 into buffer 0 ----
    float4 p0 = *reinterpret_cast<const float4*>(xin + ga0);
    float4 p1;
    if (has2) p1 = *reinterpret_cast<const float4*>(xin + ga1);
    s_in[0][f0] = p0;
    if (has2) s_in[0][f1] = p1;
    __syncthreads();

    #pragma unroll
    for (int ii = 0; ii < 6; ++ii) {
        const int cur = ii & 1;

        // issue next channel's global loads EARLY (latency hides under FMAs)
        if (ii < 5) {
            const float* xc = xin + (size_t)(ii + 1) * 65536;
            p0 = *reinterpret_cast<const float4*>(xc + ga0);
            if (has2) p1 = *reinterpret_cast<const float4*>(xc + ga1);
        }

        // ---- compute channel ii from s_in[cur] ----
        const float* sb = reinterpret_cast<const float*>(&s_in[cur][0]);
        #pragma unroll 1   // keep code size bounded; ii must stay unrolled (CONN const-indexed)
        for (int r = 0; r < 5; ++r) {
            const float* src = sb + (ty + r) * IN_T + tx * PX;
            float4 wa = *reinterpret_cast<const float4*>(src);
            float4 wb = *reinterpret_cast<const float4*>(src + 4);
            float win[8] = {wa.x, wa.y, wa.z, wa.w, wb.x, wb.y, wb.z, wb.w};
            // weights: wave-uniform global reads -> s_load (scalar pipe, L1-hot)
            const float* wrow = w + ii * 25 + r * 5;  // + j*150 + kx
            #pragma unroll
            for (int kx = 0; kx < 5; ++kx) {
                #pragma unroll
                for (int j = 0; j < 10; ++j) {
                    float wv = wrow[j * 150 + kx];
                    const int c = CONN[ii][j];
                    #pragma unroll
                    for (int p = 0; p < PX; ++p)
                        acc[p][c] = fmaf(win[kx + p], wv, acc[p][c]);
                }
            }
        }

        // write prefetched channel into the other buffer, then barrier
        if (ii < 5) {
            s_in[cur ^ 1][f0] = p0;
            if (has2) s_in[cur ^ 1][f1] = p1;
        }
        __syncthreads();
    }

    // ---- epilogue: bias*count, float4 stores ----
    const int oy = y0 + ty;
    const int ox = x0 + tx * PX;
    if (oy < 252 && ox + 3 < 252) {
        float* op = out + (size_t)n * 16 * 63504 + (size_t)oy * 252 + ox;
        #pragma unroll
        for (int c = 0; c < 16; ++c) {
            float b = bias[c] * (float)CNT[c];
            float4 v = make_float4(acc[0][c] + b, acc[1][c] + b,
                                   acc[2][c] + b, acc[3][c] + b);
            *reinterpret_cast<float4*>(op + (size_t)c * 63504) = v;
        }
    }
}

extern "C" void kernel_launch(void* const* d_in, const int* in_sizes, int n_in,
                              void* d_out, int out_size, void* d_ws, size_t ws_size,
                              hipStream_t stream) {
    const float* x    = (const float*)d_in[0];  // (64,6,256,256)
    const float* w    = (const float*)d_in[1];  // (10,6,5,5)
    const float* bias = (const float*)d_in[2];  // (1,16,1,1)
    float* out = (float*)d_out;                 // (64,16,252,252)

    dim3 grid(8, 8, 64);
    dim3 block(256);
    hipLaunchKernelGGL(c3_kernel, grid, block, 0, stream, x, w, bias, out);
}